// Round 6
// baseline (313.384 us; speedup 1.0000x reference)
//
#include <hip/hip_runtime.h>
#include <math.h>

namespace {
constexpr int NLEVELS = 16;
constexpr int NPOINTS = 200000;
constexpr long long NENT = 524309;   // next prime >= 2^19 (matches reference)
constexpr int TOTAL = NPOINTS * NLEVELS;

struct Meta {
    int   en[NLEVELS];    // per-axis grid resolution per level
    float rcp[NLEVELS];   // f32(1 / es_f32): XLA-CPU fast-math (arcp) reciprocal
    int   start_hash;     // first level using the spatial hash
};
}  // namespace

// Strict-f32 transcription with ONE change vs round 3: float_xyz is computed
// as (x+1) * rcp(es) instead of (x+1) / es, mimicking XLA CPU fast-math's
// arcp rewrite (divide-by-constant -> multiply-by-folded-reciprocal), which
// determines the corner-skip set of the np reference.
__global__ __launch_bounds__(256) void hashgrid_fwd(
    const float* __restrict__ xyz,    // (N,3) f32
    const float* __restrict__ data,   // (L, NENT, 2) f32
    float* __restrict__ out,          // (N, L*2) f32
    Meta meta)
{
    const int idx = blockIdx.x * 256 + threadIdx.x;   // point*16 + level
    if (idx >= TOTAL) return;
    const int level = idx & (NLEVELS - 1);
    const int point = idx >> 4;

    const float rcp = meta.rcp[level];
    const int   en = meta.en[level];
    const bool  is_hash = (level >= meta.start_hash);
    const int   hi = en - 1;

    // float_xyz = (xyz + 1) * (1/es)  -- plain mul, no FMA contraction
    const float fx = __fmul_rn(__fadd_rn(xyz[point * 3 + 0], 1.0f), rcp);
    const float fy = __fmul_rn(__fadd_rn(xyz[point * 3 + 1], 1.0f), rcp);
    const float fz = __fmul_rn(__fadd_rn(xyz[point * 3 + 2], 1.0f), rcp);

    // offset from pre-clip corner 0
    const int bx = (int)fx;
    const int by = (int)fy;
    const int bz = (int)fz;
    const float tx = __fsub_rn(fx, (float)bx);
    const float ty = __fsub_rn(fy, (float)by);
    const float tz = __fsub_rn(fz, (float)bz);

    const long long lvl_base = (long long)level * NENT * 2;

    float acc0 = 0.0f, acc1 = 0.0f;

    // corners in reference OFFSETS order: bit2=x, bit1=y, bit0=z
#pragma unroll
    for (int corner = 0; corner < 8; ++corner) {
        const float ox = (float)((corner >> 2) & 1);
        const float oy = (float)((corner >> 1) & 1);
        const float oz = (float)(corner & 1);

        // per-corner truncation of (f + off), THEN clip (reference quirk kept)
        int ix = (int)__fadd_rn(fx, ox);
        int iy = (int)__fadd_rn(fy, oy);
        int iz = (int)__fadd_rn(fz, oz);
        ix = ix < 0 ? 0 : (ix > hi ? hi : ix);
        iy = iy < 0 ? 0 : (iy > hi ? hi : iy);
        iz = iz < 0 ? 0 : (iz > hi ? hi : iz);

        long long ind;
        if (is_hash) {
            const long long h = ((long long)ix * 1LL)
                              ^ ((long long)iy * 19349663LL)
                              ^ ((long long)iz * 83492791LL);
            ind = h % NENT;   // nonneg operands: trunc-mod == floor-mod
        } else {
            const long long n = (long long)en;
            ind = (long long)ix * n * n + (long long)iy * n + (long long)iz;
        }

        float wxc = (ox == 0.0f) ? __fsub_rn(1.0f, tx) : tx;
        float wyc = (oy == 0.0f) ? __fsub_rn(1.0f, ty) : ty;
        float wzc = (oz == 0.0f) ? __fsub_rn(1.0f, tz) : tz;
        wxc = fminf(fmaxf(wxc, 0.0f), 1.0f);
        wyc = fminf(fmaxf(wyc, 0.0f), 1.0f);
        wzc = fminf(fmaxf(wzc, 0.0f), 1.0f);
        const float w = __fmul_rn(__fmul_rn(wxc, wyc), wzc);

        const long long eb = lvl_base + ind * 2;
        acc0 = __fadd_rn(acc0, __fmul_rn(w, data[eb]));
        acc1 = __fadd_rn(acc1, __fmul_rn(w, data[eb + 1]));
    }

    const long long ob = (long long)idx * 2;
    out[ob]     = acc0;
    out[ob + 1] = acc1;
}

static Meta compute_meta() {
    // _grid_meta() replicated in f64 on the container glibc (proven matching),
    // plus the f32 reciprocal exactly as LLVM would constant-fold it.
    Meta m{};
    int sh = NLEVELS;
    for (int i = 0; i < NLEVELS; ++i) {
        const double res = 16.0 * pow(1.38, (double)i);       // BASE_RES * B**i
        const long long vn = (long long)pow(res, 3.0);        // int((...)**3), trunc
        const double vs = pow(8.0 / (double)vn, 1.0 / 3.0);   // voxel size
        const long long en = (long long)(2.0 / vs);           // astype(int64), trunc
        m.en[i] = (int)en;
        const float es_f32 = (float)(2.0 / (double)(en - 1)); // ENTRYS_SIZE -> f32
        m.rcp[i] = 1.0f / es_f32;                             // IEEE f32 fold of 1/es
        if (sh == NLEVELS && vn > NENT) sh = i;               // first vn > N_ENTRIES
    }
    m.start_hash = sh;
    return m;
}

extern "C" void kernel_launch(void* const* d_in, const int* in_sizes, int n_in,
                              void* d_out, int out_size, void* d_ws, size_t ws_size,
                              hipStream_t stream) {
    const float* xyz  = (const float*)d_in[0];
    const float* data = (const float*)d_in[1];
    float* out = (float*)d_out;

    const Meta meta = compute_meta();

    const int blocks = (TOTAL + 255) / 256;
    hipLaunchKernelGGL(hashgrid_fwd, dim3(blocks), dim3(256), 0, stream,
                       xyz, data, out, meta);
}

// Round 7
// 242.267 us; speedup vs baseline: 1.2935x; 1.2935x over previous
//
#include <hip/hip_runtime.h>
#include <math.h>

namespace {
constexpr int NLEVELS = 16;
constexpr int NPOINTS = 200000;
constexpr long long NENT = 524309;           // next prime >= 2^19
constexpr int CHUNKS  = (NPOINTS + 255) / 256;   // 782 point-chunks per level
constexpr int PPB_T   = 128;                 // points per transpose block

struct Meta {
    int   en[NLEVELS];    // per-axis grid resolution per level
    float rcp[NLEVELS];   // f32(1/es_f32): XLA-CPU arcp reciprocal (proven r6)
    int   start_hash;     // first level using the spatial hash
};
}  // namespace

// Phase 1: level-pure blocks with XCD affinity. blockIdx = chunk*16 + level;
// hardware round-robins blocks across the 8 XCDs by blockIdx%8, so level L
// always lands on XCD L%8 -> per-XCD hot set = tables (L, L+8) = 4.2-8.4 MB,
// mostly resident in that XCD's 4 MB L2 (vs 48 MB mixed-level hot set before).
// Arithmetic is byte-identical to the round-6 passing kernel.
template <bool TWOPHASE>
__global__ __launch_bounds__(256) void hashgrid_gather(
    const float* __restrict__ xyz,    // (N,3) f32
    const float* __restrict__ data,   // (L, NENT, 2) f32
    float2* __restrict__ dst,         // TWOPHASE: ws[L][N]; else out[N][16]
    Meta meta)
{
    const int level = blockIdx.x & 15;
    const int p = (blockIdx.x >> 4) * 256 + threadIdx.x;
    if (p >= NPOINTS) return;

    const float rcp = meta.rcp[level];
    const int   en  = meta.en[level];
    const bool  is_hash = (level >= meta.start_hash);   // block-uniform branch
    const int   hi  = en - 1;

    // float_xyz = (xyz + 1) * (1/es) -- plain mul (arcp), no FMA contraction
    const float fx = __fmul_rn(__fadd_rn(xyz[p * 3 + 0], 1.0f), rcp);
    const float fy = __fmul_rn(__fadd_rn(xyz[p * 3 + 1], 1.0f), rcp);
    const float fz = __fmul_rn(__fadd_rn(xyz[p * 3 + 2], 1.0f), rcp);

    // pre-clip corner-0 truncation + fractional offsets
    const int bx = (int)fx;
    const int by = (int)fy;
    const int bz = (int)fz;
    const float tx = __fsub_rn(fx, (float)bx);
    const float ty = __fsub_rn(fy, (float)by);
    const float tz = __fsub_rn(fz, (float)bz);

    const float2* __restrict__ tbl =
        reinterpret_cast<const float2*>(data) + (size_t)level * (size_t)NENT;

    float acc0 = 0.0f, acc1 = 0.0f;

    // corners in reference OFFSETS order: bit2=x, bit1=y, bit0=z
#pragma unroll
    for (int corner = 0; corner < 8; ++corner) {
        const float ox = (float)((corner >> 2) & 1);
        const float oy = (float)((corner >> 1) & 1);
        const float oz = (float)(corner & 1);

        // per-corner truncation of (f + off), THEN clip (reference quirk)
        int ix = (int)__fadd_rn(fx, ox);
        int iy = (int)__fadd_rn(fy, oy);
        int iz = (int)__fadd_rn(fz, oz);
        ix = ix < 0 ? 0 : (ix > hi ? hi : ix);
        iy = iy < 0 ? 0 : (iy > hi ? hi : iy);
        iz = iz < 0 ? 0 : (iz > hi ? hi : iz);

        long long ind;
        if (is_hash) {
            const long long h = ((long long)ix * 1LL)
                              ^ ((long long)iy * 19349663LL)
                              ^ ((long long)iz * 83492791LL);
            ind = h % NENT;   // nonneg operands: trunc-mod == floor-mod
        } else {
            const long long n = (long long)en;
            ind = (long long)ix * n * n + (long long)iy * n + (long long)iz;
        }

        float wxc = (ox == 0.0f) ? __fsub_rn(1.0f, tx) : tx;
        float wyc = (oy == 0.0f) ? __fsub_rn(1.0f, ty) : ty;
        float wzc = (oz == 0.0f) ? __fsub_rn(1.0f, tz) : tz;
        wxc = fminf(fmaxf(wxc, 0.0f), 1.0f);
        wyc = fminf(fmaxf(wyc, 0.0f), 1.0f);
        wzc = fminf(fmaxf(wzc, 0.0f), 1.0f);
        const float w = __fmul_rn(__fmul_rn(wxc, wyc), wzc);

        const float2 v = tbl[(int)ind];
        acc0 = __fadd_rn(acc0, __fmul_rn(w, v.x));
        acc1 = __fadd_rn(acc1, __fmul_rn(w, v.y));
    }

    const float2 r = make_float2(acc0, acc1);
    if (TWOPHASE) {
        dst[(size_t)level * NPOINTS + p] = r;    // coalesced level-major
    } else {
        dst[(size_t)p * NLEVELS + level] = r;    // fallback: scattered direct
    }
}

// Phase 2: [L][N] float2 -> [N][L*2] float via LDS tile; both sides coalesced.
__global__ __launch_bounds__(256) void transpose_out(
    const float2* __restrict__ ws2,   // [16][NPOINTS]
    float4* __restrict__ out4)        // [NPOINTS][8]
{
    __shared__ float lds[PPB_T * 36];   // 36-float rows: 144B = 16B-aligned
    const int p0 = blockIdx.x * PPB_T;
    const int t  = threadIdx.x;

    // load: 8 float2/thread; per step all lanes read one level's contiguous run
#pragma unroll
    for (int i = 0; i < 8; ++i) {
        const int idx = i * 256 + t;
        const int lvl = idx >> 7;          // 0..15
        const int pl  = idx & 127;
        const int p   = p0 + pl;
        const float2 v = (p < NPOINTS) ? ws2[(size_t)lvl * NPOINTS + p]
                                       : make_float2(0.0f, 0.0f);
        lds[pl * 36 + lvl * 2 + 0] = v.x;
        lds[pl * 36 + lvl * 2 + 1] = v.y;
    }
    __syncthreads();

    // store: 4 float4/thread; a block tile is 16KB contiguous in out
#pragma unroll
    for (int j = 0; j < 4; ++j) {
        const int fidx = j * 256 + t;      // float4 index in tile
        const int pl = fidx >> 3;
        const int c  = fidx & 7;
        const int p  = p0 + pl;
        if (p < NPOINTS) {
            const float* s = &lds[pl * 36 + c * 4];
            out4[(size_t)p * 8 + c] = make_float4(s[0], s[1], s[2], s[3]);
        }
    }
}

static Meta compute_meta() {
    // _grid_meta() op-for-op in f64 + IEEE-f32 reciprocal (r6-proven).
    Meta m{};
    int sh = NLEVELS;
    for (int i = 0; i < NLEVELS; ++i) {
        const double res = 16.0 * pow(1.38, (double)i);
        const long long vn = (long long)pow(res, 3.0);
        const double vs = pow(8.0 / (double)vn, 1.0 / 3.0);
        const long long en = (long long)(2.0 / vs);
        m.en[i] = (int)en;
        const float es_f32 = (float)(2.0 / (double)(en - 1));
        m.rcp[i] = 1.0f / es_f32;
        if (sh == NLEVELS && vn > NENT) sh = i;
    }
    m.start_hash = sh;
    return m;
}

extern "C" void kernel_launch(void* const* d_in, const int* in_sizes, int n_in,
                              void* d_out, int out_size, void* d_ws, size_t ws_size,
                              hipStream_t stream) {
    const float* xyz  = (const float*)d_in[0];
    const float* data = (const float*)d_in[1];

    const Meta meta = compute_meta();
    const int gblocks = CHUNKS * 16;
    const size_t ws_need = (size_t)NLEVELS * NPOINTS * sizeof(float2);  // 25.6 MB

    if (ws_size >= ws_need) {
        hipLaunchKernelGGL((hashgrid_gather<true>), dim3(gblocks), dim3(256), 0, stream,
                           xyz, data, (float2*)d_ws, meta);
        const int tblocks = (NPOINTS + PPB_T - 1) / PPB_T;
        hipLaunchKernelGGL(transpose_out, dim3(tblocks), dim3(256), 0, stream,
                           (const float2*)d_ws, (float4*)d_out);
    } else {
        hipLaunchKernelGGL((hashgrid_gather<false>), dim3(gblocks), dim3(256), 0, stream,
                           xyz, data, (float2*)d_out, meta);
    }
}